// Round 5
// baseline (219.511 us; speedup 1.0000x reference)
//
#include <hip/hip_runtime.h>
#include <stdint.h>

typedef __attribute__((ext_vector_type(8))) short short8;
typedef __attribute__((ext_vector_type(8))) unsigned short ushort8;
typedef __attribute__((ext_vector_type(4))) unsigned short usv4;
typedef __attribute__((ext_vector_type(4))) float float4v;

#define B_SZ 2
#define SEQ 512
#define D_MODEL 1024
#define D_INNER 2048
#define N_HEADS 32
#define HEAD_DIM 64
#define D_STATE 64
#define PROJ_DIM 8224   // 2*2048 + 2*2048 + 32
#define NPAD 8320       // 65*128
#define MROWS 1024      // B_SZ*SEQ

__device__ __forceinline__ unsigned short f2bf(float f) {
    unsigned u = __builtin_bit_cast(unsigned, f);
    u += 0x7fffu + ((u >> 16) & 1u);
    return (unsigned short)(u >> 16);
}

// Async global->LDS 16B (m97 path). LDS dest must be wave-uniform base + lane*16.
__device__ __forceinline__ void gld16(unsigned short* lds, const unsigned short* g) {
#if __has_builtin(__builtin_amdgcn_global_load_lds)
    __builtin_amdgcn_global_load_lds(
        (const __attribute__((address_space(1))) void*)g,
        (__attribute__((address_space(3))) void*)lds, 16, 0, 0);
#else
    *(short8*)lds = *(const short8*)g;
#endif
}

// ---------------------------------------------------------------------------
// f32 -> bf16 elementwise (for hidden). n multiple of 1024.
// ---------------------------------------------------------------------------
__global__ __launch_bounds__(256) void f32_to_bf16(
    const float* __restrict__ src, unsigned short* __restrict__ dst) {
    int i = (blockIdx.x * 256 + threadIdx.x) * 4;
    float4v v = *(const float4v*)&src[i];
    usv4 o;
    #pragma unroll
    for (int k = 0; k < 4; k++) o[k] = f2bf(v[k]);
    *(usv4*)&dst[i] = o;
}

// ---------------------------------------------------------------------------
// Transpose f32 src[R][C] -> bf16 dst[Cp][R]; rows of dst >= C zero-filled.
// grid.x = Cp/64, grid.y = R/64, 256 threads.
// ---------------------------------------------------------------------------
__global__ __launch_bounds__(256) void transpose_pad_f32(
    const float* __restrict__ src, unsigned short* __restrict__ dst,
    int R, int C) {
    __shared__ float T[64 * 68];
    int tid = threadIdx.x;
    int c0 = blockIdx.x * 64, r0 = blockIdx.y * 64;
    int row = tid >> 2, cg = (tid & 3) * 16;
    #pragma unroll
    for (int k = 0; k < 4; k++) {
        int col = cg + k * 4;
        float4v v;
        if (c0 + col + 3 < C) {
            v = *(const float4v*)&src[(size_t)(r0 + row) * C + c0 + col];
        } else {
            #pragma unroll
            for (int e = 0; e < 4; e++)
                v[e] = (c0 + col + e < C) ? src[(size_t)(r0 + row) * C + c0 + col + e] : 0.f;
        }
        *(float4v*)&T[row * 68 + col] = v;
    }
    __syncthreads();
    int drow = tid >> 2, sg = (tid & 3) * 16;
    ushort8 v[2];
    #pragma unroll
    for (int k = 0; k < 16; k++) v[k >> 3][k & 7] = f2bf(T[(sg + k) * 68 + drow]);
    unsigned short* d = &dst[(size_t)(c0 + drow) * R + r0 + sg];
    *(ushort8*)&d[0] = v[0];
    *(ushort8*)&d[8] = v[1];
}

// ---------------------------------------------------------------------------
// GEMM: C[M][N] = A[M][K] @ Bt[N][K]^T (bf16), f32 out. 128x128 tile, 4 waves,
// BK=64, async global_load_lds staging with XOR bank swizzle:
//   LDS phys layout [128 rows][8 groups of 8 shorts]; phys_group = logical ^ (row&7).
//   Writes are forced to lane*16B; we swizzle by fetching the XOR'd logical
//   group on the GLOBAL side. Readers un-swizzle -> 2-way banks (free, m136).
// Split-K via gridDim.z (klen multiple of 64), partial to Cout + z*M*N.
// ---------------------------------------------------------------------------
__global__ __launch_bounds__(256) void gemm_bt(
    const unsigned short* __restrict__ A, const unsigned short* __restrict__ Bt,
    float* __restrict__ Cout, int M, int N, int K, int klen) {
    __shared__ unsigned short As[8192];
    __shared__ unsigned short Bs[8192];
    int tid = threadIdx.x;
    int lane = tid & 63, w = tid >> 6, quad = lane >> 4, l15 = lane & 15;
    int m0 = blockIdx.y * 128, n0 = blockIdx.x * 128;
    int kb = blockIdx.z * klen, ke = kb + klen;
    float* Cz = Cout + (size_t)blockIdx.z * M * N;
    int wm = (w & 1) * 64, wn = (w >> 1) * 64;
    float4v acc[4][4];
    #pragma unroll
    for (int i = 0; i < 4; i++)
        #pragma unroll
        for (int j = 0; j < 4; j++) acc[i][j] = (float4v){0.f, 0.f, 0.f, 0.f};

    int rs = tid >> 3;                              // row 0..31 within pass group
    int gl = ((tid & 7) ^ (rs & 7)) * 8;            // swizzled logical col (shorts)
    const unsigned short* ap = &A [(size_t)(m0 + rs) * K + gl];
    const unsigned short* bp = &Bt[(size_t)(n0 + rs) * K + gl];
    int rx = l15 & 7;                               // reader row&7

    for (int k0 = kb; k0 < ke; k0 += 64) {
        __syncthreads();
        #pragma unroll
        for (int p = 0; p < 4; p++) {
            gld16(&As[p * 2048 + tid * 8], ap + (size_t)(p * 32) * K + k0);
            gld16(&Bs[p * 2048 + tid * 8], bp + (size_t)(p * 32) * K + k0);
        }
        __syncthreads();
        #pragma unroll
        for (int kq = 0; kq < 2; kq++) {
            short8 af[4], bfr[4];
            #pragma unroll
            for (int mt = 0; mt < 4; mt++)
                af[mt] = *(const short8*)&As[(wm + mt * 16 + l15) * 64 + (((kq << 2) + quad) ^ rx) * 8];
            #pragma unroll
            for (int nt = 0; nt < 4; nt++)
                bfr[nt] = *(const short8*)&Bs[(wn + nt * 16 + l15) * 64 + (((kq << 2) + quad) ^ rx) * 8];
            #pragma unroll
            for (int mt = 0; mt < 4; mt++)
                #pragma unroll
                for (int nt = 0; nt < 4; nt++)
                    acc[mt][nt] = __builtin_amdgcn_mfma_f32_16x16x32_bf16(
                        af[mt], bfr[nt], acc[mt][nt], 0, 0, 0);
        }
    }
    #pragma unroll
    for (int mt = 0; mt < 4; mt++)
        #pragma unroll
        for (int nt = 0; nt < 4; nt++)
            #pragma unroll
            for (int r = 0; r < 4; r++) {
                int row = m0 + wm + mt * 16 + quad * 4 + r;
                int col = n0 + wn + nt * 16 + l15;
                if (col < N)
                    Cz[(size_t)row * N + col] = acc[mt][nt][r];
            }
}

// ---------------------------------------------------------------------------
// reduce 4 split-K partials -> f32 out. n/1024 blocks x 256 threads, float4.
// ---------------------------------------------------------------------------
__global__ __launch_bounds__(256) void reduce4(
    const float* __restrict__ P, float* __restrict__ out, int n) {
    int i = (blockIdx.x * 256 + threadIdx.x) * 4;
    float4v s = *(const float4v*)&P[i];
    #pragma unroll
    for (int z = 1; z < 4; z++) {
        float4v v = *(const float4v*)&P[(size_t)z * n + i];
        #pragma unroll
        for (int k = 0; k < 4; k++) s[k] += v[k];
    }
    *(float4v*)&out[i] = s;
}

// ---------------------------------------------------------------------------
// dt softplus + inclusive cumsum per (b,h). 64 blocks x 64 threads (1 wave).
// ---------------------------------------------------------------------------
__global__ __launch_bounds__(64) void dt_scan(
    const float* __restrict__ proj, const float* __restrict__ dt_bias,
    float* __restrict__ dt_arr, float* __restrict__ cum_arr) {
    int bh = blockIdx.x;
    int b = bh >> 5, h = bh & 31;
    int lane = threadIdx.x;
    float bias = dt_bias[h];
    float carry = 0.f;
    for (int c = 0; c < 8; c++) {
        int t = c * 64 + lane;
        float raw = proj[(size_t)(b * SEQ + t) * PROJ_DIM + 8192 + h] + bias;
        float dt = raw > 20.f ? raw : log1pf(expf(raw));
        dt_arr[bh * SEQ + t] = dt;
        float v = dt;
        #pragma unroll
        for (int d = 1; d < 64; d <<= 1) {
            float nv = __shfl_up(v, d, 64);
            if (lane >= d) v += nv;
        }
        float cum = carry + v;
        cum_arr[bh * SEQ + t] = cum;
        carry = __shfl(cum, 63, 64);
    }
}

// ---------------------------------------------------------------------------
// RoPE B,C and pack to bf16 [bh][t][64]. 1024 blocks (b*SEQ) x 256 threads.
// ---------------------------------------------------------------------------
__global__ __launch_bounds__(256) void rope_pack(
    const float* __restrict__ proj, const float* __restrict__ cum_arr,
    unsigned short* __restrict__ Bh, unsigned short* __restrict__ Ch) {
    int m = blockIdx.x;
    int b = m >> 9, t = m & 511;
    int tid = threadIdx.x;
    const float k_l2 = 13.287712379549449f / 32.f;  // log2(10000)/half
    #pragma unroll
    for (int i = 0; i < 4; i++) {
        int q = i * 256 + tid;
        int h = q >> 5, j = q & 31;
        float cum = cum_arr[(b * 32 + h) * SEQ + t];
        float th = cum * exp2f(-(float)j * k_l2);
        float s, c;
        sincosf(th, &s, &c);
        const float* pb = proj + (size_t)m * PROJ_DIM + 4096 + h * 64;
        const float* pc = proj + (size_t)m * PROJ_DIM + 6144 + h * 64;
        size_t dst = ((size_t)(b * 32 + h) * SEQ + t) * 64;
        float b0 = pb[2 * j], b1 = pb[2 * j + 1];
        Bh[dst + 2 * j]     = f2bf(b0 * c - b1 * s);
        Bh[dst + 2 * j + 1] = f2bf(b0 * s + b1 * c);
        float c0 = pc[2 * j], c1 = pc[2 * j + 1];
        Ch[dst + 2 * j]     = f2bf(c0 * c - c1 * s);
        Ch[dst + 2 * j + 1] = f2bf(c0 * s + c1 * c);
    }
}

// ---------------------------------------------------------------------------
// x -> Xt[bh][p=64][s=512] bf16 (transposed for B-operand of P@V).
// grid (8 s-chunks, 64 bh), 256 threads.
// ---------------------------------------------------------------------------
__global__ __launch_bounds__(256) void x_transpose(
    const float* __restrict__ proj, unsigned short* __restrict__ Xt) {
    __shared__ float T[64 * 68];
    int bh = blockIdx.y;
    int b = bh >> 5, h = bh & 31;
    int s0 = blockIdx.x * 64;
    int tid = threadIdx.x;
    int r = tid >> 2, cg = tid & 3;
    const float* src = proj + (size_t)(b * SEQ + s0 + r) * PROJ_DIM + 2048 + h * 64 + cg * 16;
    #pragma unroll
    for (int k = 0; k < 4; k++)
        *(float4v*)&T[r * 68 + cg * 16 + k * 4] = *(const float4v*)&src[k * 4];
    __syncthreads();
    int p = tid >> 2, sg = tid & 3;
    ushort8 v[2];
    #pragma unroll
    for (int k = 0; k < 16; k++) v[k >> 3][k & 7] = f2bf(T[(sg * 16 + k) * 68 + p]);
    unsigned short* dst = Xt + ((size_t)bh * 64 + p) * SEQ + s0 + sg * 16;
    *(ushort8*)&dst[0] = v[0];
    *(ushort8*)&dst[8] = v[1];
}

// ---------------------------------------------------------------------------
// Decay-attention: y[b,t,h*64+p] = sum_{s<=t} exp(A(ct-cs))*0.5*(dt_s+[s<t]dt_{s+1})
//                                   * (C_t . B_s) * x_s[p]
// grid (8 q-tiles, 64 bh), 256 threads (4 waves x 16 q-rows).
// ---------------------------------------------------------------------------
__global__ __launch_bounds__(256) void attn_scan(
    const unsigned short* __restrict__ Bh, const unsigned short* __restrict__ Ch,
    const unsigned short* __restrict__ Xt, const float* __restrict__ dt_arr,
    const float* __restrict__ cum_arr, const float* __restrict__ A_log,
    float* __restrict__ y_ws) {
    __shared__ unsigned short Bs[4096];
    __shared__ unsigned short Xs[4096];
    __shared__ unsigned short Ps[4096];
    int qt = blockIdx.x, bh = blockIdx.y;
    int b = bh >> 5, h = bh & 31;
    float Aneg = -expf(A_log[h]);
    int tid = threadIdx.x, lane = tid & 63, w = tid >> 6;
    int quad = lane >> 4, l15 = lane & 15;

    int qrow = qt * 64 + w * 16 + l15;
    const unsigned short* Cptr = Ch + ((size_t)bh * SEQ + qrow) * 64;
    short8 cf[2];
    cf[0] = *(const short8*)&Cptr[quad * 8];
    cf[1] = *(const short8*)&Cptr[32 + quad * 8];

    int trow[4];
    float cumt[4];
    #pragma unroll
    for (int r = 0; r < 4; r++) {
        trow[r] = qt * 64 + w * 16 + quad * 4 + r;
        cumt[r] = cum_arr[bh * SEQ + trow[r]];
    }
    float4v yacc[4];
    #pragma unroll
    for (int i = 0; i < 4; i++) yacc[i] = (float4v){0.f, 0.f, 0.f, 0.f};

    for (int st = 0; st <= qt; st++) {
        __syncthreads();
        const unsigned short* bsrc = Bh + ((size_t)bh * SEQ + st * 64) * 64;
        gld16(&Bs[tid * 8],         bsrc + tid * 8);
        gld16(&Bs[(tid + 256) * 8], bsrc + (tid + 256) * 8);
        const unsigned short* xsrc = Xt + (size_t)bh * 64 * SEQ + st * 64;
        {
            int e = tid;
            int p = e >> 3, so = (e & 7) * 8;
            gld16(&Xs[p * 64 + so], xsrc + (size_t)p * SEQ + so);
            e = tid + 256;
            p = e >> 3; so = (e & 7) * 8;
            gld16(&Xs[p * 64 + so], xsrc + (size_t)p * SEQ + so);
        }
        __syncthreads();
        float4v sacc[4];
        #pragma unroll
        for (int i = 0; i < 4; i++) sacc[i] = (float4v){0.f, 0.f, 0.f, 0.f};
        #pragma unroll
        for (int kk = 0; kk < 2; kk++)
            #pragma unroll
            for (int nt = 0; nt < 4; nt++) {
                short8 bf8 = *(const short8*)&Bs[(nt * 16 + l15) * 64 + kk * 32 + quad * 8];
                sacc[nt] = __builtin_amdgcn_mfma_f32_16x16x32_bf16(cf[kk], bf8, sacc[nt], 0, 0, 0);
            }
        #pragma unroll
        for (int nt = 0; nt < 4; nt++) {
            int s = st * 64 + nt * 16 + l15;
            float cums = cum_arr[bh * SEQ + s];
            float dts = dt_arr[bh * SEQ + s];
            float dts1 = (s + 1 < SEQ) ? dt_arr[bh * SEQ + s + 1] : 0.f;
            #pragma unroll
            for (int r = 0; r < 4; r++) {
                int t = trow[r];
                float wgt = (s > t) ? 0.f
                          : expf(Aneg * (cumt[r] - cums)) * 0.5f * (dts + ((s < t) ? dts1 : 0.f));
                Ps[w * 1024 + (quad * 4 + r) * 64 + nt * 16 + l15] = f2bf(sacc[nt][r] * wgt);
            }
        }
        __syncthreads();
        #pragma unroll
        for (int kk = 0; kk < 2; kk++) {
            short8 af = *(const short8*)&Ps[w * 1024 + l15 * 64 + kk * 32 + quad * 8];
            #pragma unroll
            for (int pt = 0; pt < 4; pt++) {
                short8 xf = *(const short8*)&Xs[(pt * 16 + l15) * 64 + kk * 32 + quad * 8];
                yacc[pt] = __builtin_amdgcn_mfma_f32_16x16x32_bf16(af, xf, yacc[pt], 0, 0, 0);
            }
        }
    }
    #pragma unroll
    for (int pt = 0; pt < 4; pt++)
        #pragma unroll
        for (int r = 0; r < 4; r++) {
            int t = trow[r];
            int p = pt * 16 + l15;
            y_ws[((size_t)b * SEQ + t) * D_INNER + h * 64 + p] = yacc[pt][r];
        }
}

// ---------------------------------------------------------------------------
// y = y*silu(z); rmsnorm; write bf16. 1024 blocks x 256 threads.
// ---------------------------------------------------------------------------
__global__ __launch_bounds__(256) void gated_rmsnorm(
    const float* __restrict__ y_ws, const float* __restrict__ proj,
    const float* __restrict__ nw, unsigned short* __restrict__ Y2) {
    __shared__ float red[4];
    int m = blockIdx.x, tid = threadIdx.x;
    const float* yrow = y_ws + (size_t)m * D_INNER;
    const float* zrow = proj + (size_t)m * PROJ_DIM;
    int j0 = tid * 8;
    float v[8];
    float ss = 0.f;
    #pragma unroll
    for (int k = 0; k < 8; k++) {
        float y = yrow[j0 + k];
        float z = zrow[j0 + k];
        float g = y * (z / (1.f + expf(-z)));
        v[k] = g;
        ss += g * g;
    }
    #pragma unroll
    for (int d = 32; d > 0; d >>= 1) ss += __shfl_down(ss, d, 64);
    if ((tid & 63) == 0) red[tid >> 6] = ss;
    __syncthreads();
    float tot = red[0] + red[1] + red[2] + red[3];
    float inv = 1.0f / sqrtf(tot / (float)D_INNER + 1e-6f);
    #pragma unroll
    for (int k = 0; k < 8; k++)
        Y2[(size_t)m * D_INNER + j0 + k] = f2bf(v[k] * inv * nw[j0 + k]);
}

// ---------------------------------------------------------------------------

extern "C" void kernel_launch(void* const* d_in, const int* in_sizes, int n_in,
                              void* d_out, int out_size, void* d_ws, size_t ws_size,
                              hipStream_t stream) {
    const float* hidden   = (const float*)d_in[0];
    const float* W_in     = (const float*)d_in[1];
    const float* dt_bias  = (const float*)d_in[2];
    const float* A_log    = (const float*)d_in[3];
    const float* norm_w   = (const float*)d_in[4];
    const float* W_out    = (const float*)d_in[5];
    float* out = (float*)d_out;

    char* ws = (char*)d_ws;
    unsigned short* Wt1 = (unsigned short*)(ws);                 // 8320*1024 bf16 = 17,039,360
    unsigned short* Hb  = (unsigned short*)(ws + 17039360);      // 1024*1024 bf16 = 2,097,152
    float* proj         = (float*)(ws + 19136512);               // 1024*8224 f32 = 33,685,504
    float* dt_arr       = (float*)(ws + 52822016);               // 64*512 f32    = 131,072
    float* cum_arr      = (float*)(ws + 52953088);               // 131,072
    unsigned short* Bh  = (unsigned short*)(ws + 53084160);      // 64*512*64 bf16 = 4,194,304
    unsigned short* Ch  = (unsigned short*)(ws + 57278464);      // 4,194,304
    unsigned short* Xt  = (unsigned short*)(ws + 61472768);      // 4,194,304
    float* y_ws         = (float*)(ws + 65667072);               // 1024*2048 f32 = 8,388,608
    unsigned short* Y2  = (unsigned short*)(ws + 74055680);      // 1024*2048 bf16 = 4,194,304
    unsigned short* Wt2 = (unsigned short*)(ws + 78249984);      // 1024*2048 bf16 = 4,194,304
    // total 82,444,288 bytes
    float* Pk = proj;  // reuse proj (free after gated_rmsnorm) for 4x4MB split-K partials

    // hidden f32 -> bf16
    f32_to_bf16<<<MROWS * D_MODEL / 1024, 256, 0, stream>>>(hidden, Hb);
    // W_in [1024][8224] f32 -> Wt1 [8320][1024] bf16 (padded rows zeroed)
    transpose_pad_f32<<<dim3(NPAD / 64, D_MODEL / 64), 256, 0, stream>>>(W_in, Wt1, D_MODEL, PROJ_DIM);
    // W_out [2048][1024] f32 -> Wt2 [1024][2048] bf16
    transpose_pad_f32<<<dim3(D_MODEL / 64, D_INNER / 64), 256, 0, stream>>>(W_out, Wt2, D_INNER, D_MODEL);
    // proj = hidden @ W_in   (f32 out, guarded at N=8224)
    gemm_bt<<<dim3(NPAD / 128, MROWS / 128, 1), 256, 0, stream>>>(
        Hb, Wt1, proj, MROWS, PROJ_DIM, D_MODEL, D_MODEL);
    // dt + cumsum
    dt_scan<<<64, 64, 0, stream>>>(proj, dt_bias, dt_arr, cum_arr);
    // RoPE pack B, C
    rope_pack<<<MROWS, 256, 0, stream>>>(proj, cum_arr, Bh, Ch);
    // x transpose
    x_transpose<<<dim3(8, 64), 256, 0, stream>>>(proj, Xt);
    // decay attention (the scan, reformulated)
    attn_scan<<<dim3(8, 64), 256, 0, stream>>>(Bh, Ch, Xt, dt_arr, cum_arr, A_log, y_ws);
    // gate + rmsnorm (last reader of proj/z)
    gated_rmsnorm<<<MROWS, 256, 0, stream>>>(y_ws, proj, norm_w, Y2);
    // out = Y2 @ W_out, split-K=4 partials into Pk, then reduce
    gemm_bt<<<dim3(D_MODEL / 128, MROWS / 128, 4), 256, 0, stream>>>(
        Y2, Wt2, Pk, MROWS, D_MODEL, D_INNER, D_INNER / 4);
    reduce4<<<MROWS * D_MODEL / 1024, 256, 0, stream>>>(Pk, out, MROWS * D_MODEL);
}

// Round 6
// 211.000 us; speedup vs baseline: 1.0403x; 1.0403x over previous
//
#include <hip/hip_runtime.h>
#include <stdint.h>

typedef __attribute__((ext_vector_type(8))) short short8;
typedef __attribute__((ext_vector_type(8))) unsigned short ushort8;
typedef __attribute__((ext_vector_type(4))) unsigned short usv4;
typedef __attribute__((ext_vector_type(4))) float float4v;

#define B_SZ 2
#define SEQ 512
#define D_MODEL 1024
#define D_INNER 2048
#define N_HEADS 32
#define HEAD_DIM 64
#define D_STATE 64
#define PROJ_DIM 8224   // 2*2048 + 2*2048 + 32
#define NPAD 8320       // 65*128
#define MROWS 1024      // B_SZ*SEQ

__device__ __forceinline__ unsigned short f2bf(float f) {
    unsigned u = __builtin_bit_cast(unsigned, f);
    u += 0x7fffu + ((u >> 16) & 1u);
    return (unsigned short)(u >> 16);
}
__device__ __forceinline__ float bf2f(unsigned short h) {
    return __builtin_bit_cast(float, (unsigned)h << 16);
}

// Async global->LDS 16B (m97 path). LDS dest must be wave-uniform base + lane*16.
__device__ __forceinline__ void gld16(unsigned short* lds, const unsigned short* g) {
#if __has_builtin(__builtin_amdgcn_global_load_lds)
    __builtin_amdgcn_global_load_lds(
        (const __attribute__((address_space(1))) void*)g,
        (__attribute__((address_space(3))) void*)lds, 16, 0, 0);
#else
    *(short8*)lds = *(const short8*)g;
#endif
}

// ---------------------------------------------------------------------------
// Fat prep kernel: blk<1024 -> hidden f32->bf16; then Wt1 transpose (2080
// blocks); then Wt2 transpose (512 blocks). Transpose: f32 src[R][C] ->
// bf16 dst[Cp][R], pad rows zero-filled.
// ---------------------------------------------------------------------------
__device__ void transpose_body(const float* __restrict__ src,
                               unsigned short* __restrict__ dst,
                               int R, int C, int bx, int by, float* T, int tid) {
    int c0 = bx * 64, r0 = by * 64;
    int row = tid >> 2, cg = (tid & 3) * 16;
    #pragma unroll
    for (int k = 0; k < 4; k++) {
        int col = cg + k * 4;
        float4v v;
        if (c0 + col + 3 < C) {
            v = *(const float4v*)&src[(size_t)(r0 + row) * C + c0 + col];
        } else {
            #pragma unroll
            for (int e = 0; e < 4; e++)
                v[e] = (c0 + col + e < C) ? src[(size_t)(r0 + row) * C + c0 + col + e] : 0.f;
        }
        *(float4v*)&T[row * 68 + col] = v;
    }
    __syncthreads();
    int drow = tid >> 2, sg = (tid & 3) * 16;
    ushort8 v[2];
    #pragma unroll
    for (int k = 0; k < 16; k++) v[k >> 3][k & 7] = f2bf(T[(sg + k) * 68 + drow]);
    unsigned short* d = &dst[(size_t)(c0 + drow) * R + r0 + sg];
    *(ushort8*)&d[0] = v[0];
    *(ushort8*)&d[8] = v[1];
}

__global__ __launch_bounds__(256) void prep_fat(
    const float* __restrict__ hidden, const float* __restrict__ W_in,
    const float* __restrict__ W_out, unsigned short* __restrict__ Hb,
    unsigned short* __restrict__ Wt1, unsigned short* __restrict__ Wt2) {
    __shared__ float T[64 * 68];
    int blk = blockIdx.x, tid = threadIdx.x;
    if (blk < 1024) {
        int i = blk * 1024 + tid * 4;
        float4v v = *(const float4v*)&hidden[i];
        usv4 o;
        #pragma unroll
        for (int k = 0; k < 4; k++) o[k] = f2bf(v[k]);
        *(usv4*)&Hb[i] = o;
    } else if (blk < 3104) {
        int q = blk - 1024;  // 2080 = 130 x 16
        transpose_body(W_in, Wt1, D_MODEL, PROJ_DIM, q % 130, q / 130, T, tid);
    } else {
        int q = blk - 3104;  // 512 = 16 x 32
        transpose_body(W_out, Wt2, D_INNER, D_MODEL, q % 16, q / 16, T, tid);
    }
}

// ---------------------------------------------------------------------------
// GEMM: C[M][N] = A[M][K] @ Bt[N][K]^T (bf16). 128x128 tile, 4 waves, BK=64,
// async global_load_lds + XOR bank swizzle (conflict-free, verified R5).
// Split-K via gridDim.z; BF16OUT selects output type.
// ---------------------------------------------------------------------------
template <bool BF16OUT>
__global__ __launch_bounds__(256) void gemm_bt(
    const unsigned short* __restrict__ A, const unsigned short* __restrict__ Bt,
    void* __restrict__ Cout, int M, int N, int K, int klen) {
    __shared__ unsigned short As[8192];
    __shared__ unsigned short Bs[8192];
    int tid = threadIdx.x;
    int lane = tid & 63, w = tid >> 6, quad = lane >> 4, l15 = lane & 15;
    int m0 = blockIdx.y * 128, n0 = blockIdx.x * 128;
    int kb = blockIdx.z * klen, ke = kb + klen;
    int wm = (w & 1) * 64, wn = (w >> 1) * 64;
    float4v acc[4][4];
    #pragma unroll
    for (int i = 0; i < 4; i++)
        #pragma unroll
        for (int j = 0; j < 4; j++) acc[i][j] = (float4v){0.f, 0.f, 0.f, 0.f};

    int rs = tid >> 3;
    int gl = ((tid & 7) ^ (rs & 7)) * 8;
    const unsigned short* ap = &A [(size_t)(m0 + rs) * K + gl];
    const unsigned short* bp = &Bt[(size_t)(n0 + rs) * K + gl];
    int rx = l15 & 7;

    for (int k0 = kb; k0 < ke; k0 += 64) {
        __syncthreads();
        #pragma unroll
        for (int p = 0; p < 4; p++) {
            gld16(&As[p * 2048 + tid * 8], ap + (size_t)(p * 32) * K + k0);
            gld16(&Bs[p * 2048 + tid * 8], bp + (size_t)(p * 32) * K + k0);
        }
        __syncthreads();
        #pragma unroll
        for (int kq = 0; kq < 2; kq++) {
            short8 af[4], bfr[4];
            #pragma unroll
            for (int mt = 0; mt < 4; mt++)
                af[mt] = *(const short8*)&As[(wm + mt * 16 + l15) * 64 + (((kq << 2) + quad) ^ rx) * 8];
            #pragma unroll
            for (int nt = 0; nt < 4; nt++)
                bfr[nt] = *(const short8*)&Bs[(wn + nt * 16 + l15) * 64 + (((kq << 2) + quad) ^ rx) * 8];
            #pragma unroll
            for (int mt = 0; mt < 4; mt++)
                #pragma unroll
                for (int nt = 0; nt < 4; nt++)
                    acc[mt][nt] = __builtin_amdgcn_mfma_f32_16x16x32_bf16(
                        af[mt], bfr[nt], acc[mt][nt], 0, 0, 0);
        }
    }
    #pragma unroll
    for (int mt = 0; mt < 4; mt++)
        #pragma unroll
        for (int nt = 0; nt < 4; nt++)
            #pragma unroll
            for (int r = 0; r < 4; r++) {
                int row = m0 + wm + mt * 16 + quad * 4 + r;
                int col = n0 + wn + nt * 16 + l15;
                if (col < N) {
                    if (BF16OUT)
                        ((unsigned short*)Cout)[(size_t)blockIdx.z * M * N + (size_t)row * N + col]
                            = f2bf(acc[mt][nt][r]);
                    else
                        ((float*)Cout)[(size_t)blockIdx.z * M * N + (size_t)row * N + col]
                            = acc[mt][nt][r];
                }
            }
}

// ---------------------------------------------------------------------------
// reduce 4 split-K partials -> f32 out.
// ---------------------------------------------------------------------------
__global__ __launch_bounds__(256) void reduce4(
    const float* __restrict__ P, float* __restrict__ out, int n) {
    int i = (blockIdx.x * 256 + threadIdx.x) * 4;
    float4v s = *(const float4v*)&P[i];
    #pragma unroll
    for (int z = 1; z < 4; z++) {
        float4v v = *(const float4v*)&P[(size_t)z * n + i];
        #pragma unroll
        for (int k = 0; k < 4; k++) s[k] += v[k];
    }
    *(float4v*)&out[i] = s;
}

// ---------------------------------------------------------------------------
// Per-(b,h) head prep: dt softplus + cumsum (wave0), RoPE B/C pack, x
// transpose -> Xt[bh][p][s]. 64 blocks x 256 threads. proj is bf16.
// ---------------------------------------------------------------------------
__global__ __launch_bounds__(256) void headprep(
    const unsigned short* __restrict__ proj, const float* __restrict__ dt_bias,
    float* __restrict__ dt_arr, float* __restrict__ cum_arr,
    unsigned short* __restrict__ Bh, unsigned short* __restrict__ Ch,
    unsigned short* __restrict__ Xt) {
    __shared__ float dtS[SEQ];
    __shared__ float cumS[SEQ];
    __shared__ unsigned short XT[128 * 72];
    int bh = blockIdx.x;
    int b = bh >> 5, h = bh & 31;
    int tid = threadIdx.x, lane = tid & 63, w = tid >> 6;

    // phase 1: dt + cumsum (wave 0)
    if (w == 0) {
        float bias = dt_bias[h];
        float carry = 0.f;
        for (int c = 0; c < 8; c++) {
            int t = c * 64 + lane;
            float raw = bf2f(proj[(size_t)(b * SEQ + t) * PROJ_DIM + 8192 + h]) + bias;
            float dt = raw > 20.f ? raw : log1pf(expf(raw));
            float v = dt;
            #pragma unroll
            for (int d = 1; d < 64; d <<= 1) {
                float nv = __shfl_up(v, d, 64);
                if (lane >= d) v += nv;
            }
            float cum = carry + v;
            dtS[t] = dt; cumS[t] = cum;
            dt_arr[bh * SEQ + t] = dt;
            cum_arr[bh * SEQ + t] = cum;
            carry = __shfl(cum, 63, 64);
        }
    }
    __syncthreads();

    // phase 2: RoPE pack B, C (j fixed per thread -> freq constant)
    int j = tid & 31, t8 = tid >> 5;
    const float k_l2 = 13.287712379549449f / 32.f;  // log2(10000)/half
    float freq = exp2f(-(float)j * k_l2);
    for (int pass = 0; pass < 64; pass++) {
        int t = pass * 8 + t8;
        float th = cumS[t] * freq;
        float s, c;
        __sincosf(th, &s, &c);
        size_t rb = (size_t)(b * SEQ + t) * PROJ_DIM;
        unsigned bu = *(const unsigned*)&proj[rb + 4096 + h * 64 + 2 * j];
        unsigned cu = *(const unsigned*)&proj[rb + 6144 + h * 64 + 2 * j];
        float b0 = bf2f((unsigned short)(bu & 0xffff)), b1 = bf2f((unsigned short)(bu >> 16));
        float c0 = bf2f((unsigned short)(cu & 0xffff)), c1 = bf2f((unsigned short)(cu >> 16));
        size_t dst = ((size_t)bh * SEQ + t) * 64 + 2 * j;
        unsigned ob = (unsigned)f2bf(b0 * c - b1 * s) | ((unsigned)f2bf(b0 * s + b1 * c) << 16);
        unsigned oc = (unsigned)f2bf(c0 * c - c1 * s) | ((unsigned)f2bf(c0 * s + c1 * c) << 16);
        *(unsigned*)&Bh[dst] = ob;
        *(unsigned*)&Ch[dst] = oc;
    }

    // phase 3: x -> Xt[bh][p][s] in 4 chunks of 128 t
    for (int ch = 0; ch < 4; ch++) {
        __syncthreads();
        #pragma unroll
        for (int r = 0; r < 4; r++) {
            int idx = r * 2048 + tid * 8;
            int tl = idx >> 6, pp = idx & 63;
            *(ushort8*)&XT[tl * 72 + pp] =
                *(const ushort8*)&proj[(size_t)(b * SEQ + ch * 128 + tl) * PROJ_DIM + 2048 + h * 64 + pp];
        }
        __syncthreads();
        int p = tid & 63, sq = tid >> 6;
        #pragma unroll
        for (int r = 0; r < 4; r++) {
            int s0 = r * 32 + sq * 8;
            ushort8 v;
            #pragma unroll
            for (int k = 0; k < 8; k++) v[k] = XT[(s0 + k) * 72 + p];
            *(ushort8*)&Xt[((size_t)bh * 64 + p) * SEQ + ch * 128 + s0] = v;
        }
    }
}

// ---------------------------------------------------------------------------
// Decay-attention: y[b,t,h*64+p] = sum_{s<=t} exp(A(ct-cs))*0.5*(dt_s+[s<t]dt_{s+1})
//                                   * (C_t . B_s) * x_s[p]
// grid (8 q-tiles, 64 bh), 256 threads (4 waves x 16 q-rows).
// ---------------------------------------------------------------------------
__global__ __launch_bounds__(256) void attn_scan(
    const unsigned short* __restrict__ Bh, const unsigned short* __restrict__ Ch,
    const unsigned short* __restrict__ Xt, const float* __restrict__ dt_arr,
    const float* __restrict__ cum_arr, const float* __restrict__ A_log,
    float* __restrict__ y_ws) {
    __shared__ unsigned short Bs[4096];
    __shared__ unsigned short Xs[4096];
    __shared__ unsigned short Ps[4096];
    int qt = blockIdx.x, bh = blockIdx.y;
    int b = bh >> 5, h = bh & 31;
    float Aneg = -expf(A_log[h]);
    int tid = threadIdx.x, lane = tid & 63, w = tid >> 6;
    int quad = lane >> 4, l15 = lane & 15;

    int qrow = qt * 64 + w * 16 + l15;
    const unsigned short* Cptr = Ch + ((size_t)bh * SEQ + qrow) * 64;
    short8 cf[2];
    cf[0] = *(const short8*)&Cptr[quad * 8];
    cf[1] = *(const short8*)&Cptr[32 + quad * 8];

    int trow[4];
    float cumt[4];
    #pragma unroll
    for (int r = 0; r < 4; r++) {
        trow[r] = qt * 64 + w * 16 + quad * 4 + r;
        cumt[r] = cum_arr[bh * SEQ + trow[r]];
    }
    float4v yacc[4];
    #pragma unroll
    for (int i = 0; i < 4; i++) yacc[i] = (float4v){0.f, 0.f, 0.f, 0.f};

    for (int st = 0; st <= qt; st++) {
        __syncthreads();
        const unsigned short* bsrc = Bh + ((size_t)bh * SEQ + st * 64) * 64;
        gld16(&Bs[tid * 8],         bsrc + tid * 8);
        gld16(&Bs[(tid + 256) * 8], bsrc + (tid + 256) * 8);
        const unsigned short* xsrc = Xt + (size_t)bh * 64 * SEQ + st * 64;
        {
            int e = tid;
            int p = e >> 3, so = (e & 7) * 8;
            gld16(&Xs[p * 64 + so], xsrc + (size_t)p * SEQ + so);
            e = tid + 256;
            p = e >> 3; so = (e & 7) * 8;
            gld16(&Xs[p * 64 + so], xsrc + (size_t)p * SEQ + so);
        }
        __syncthreads();
        float4v sacc[4];
        #pragma unroll
        for (int i = 0; i < 4; i++) sacc[i] = (float4v){0.f, 0.f, 0.f, 0.f};
        #pragma unroll
        for (int kk = 0; kk < 2; kk++)
            #pragma unroll
            for (int nt = 0; nt < 4; nt++) {
                short8 bf8 = *(const short8*)&Bs[(nt * 16 + l15) * 64 + kk * 32 + quad * 8];
                sacc[nt] = __builtin_amdgcn_mfma_f32_16x16x32_bf16(cf[kk], bf8, sacc[nt], 0, 0, 0);
            }
        #pragma unroll
        for (int nt = 0; nt < 4; nt++) {
            int s = st * 64 + nt * 16 + l15;
            float cums = cum_arr[bh * SEQ + s];
            float dts = dt_arr[bh * SEQ + s];
            float dts1 = (s + 1 < SEQ) ? dt_arr[bh * SEQ + s + 1] : 0.f;
            #pragma unroll
            for (int r = 0; r < 4; r++) {
                int t = trow[r];
                float wgt = (s > t) ? 0.f
                          : expf(Aneg * (cumt[r] - cums)) * 0.5f * (dts + ((s < t) ? dts1 : 0.f));
                Ps[w * 1024 + (quad * 4 + r) * 64 + nt * 16 + l15] = f2bf(sacc[nt][r] * wgt);
            }
        }
        __syncthreads();
        #pragma unroll
        for (int kk = 0; kk < 2; kk++) {
            short8 af = *(const short8*)&Ps[w * 1024 + l15 * 64 + kk * 32 + quad * 8];
            #pragma unroll
            for (int pt = 0; pt < 4; pt++) {
                short8 xf = *(const short8*)&Xs[(pt * 16 + l15) * 64 + kk * 32 + quad * 8];
                yacc[pt] = __builtin_amdgcn_mfma_f32_16x16x32_bf16(af, xf, yacc[pt], 0, 0, 0);
            }
        }
    }
    #pragma unroll
    for (int pt = 0; pt < 4; pt++)
        #pragma unroll
        for (int r = 0; r < 4; r++) {
            int t = trow[r];
            int p = pt * 16 + l15;
            y_ws[((size_t)b * SEQ + t) * D_INNER + h * 64 + p] = yacc[pt][r];
        }
}

// ---------------------------------------------------------------------------
// y = y*silu(z); rmsnorm; write bf16. z from bf16 proj. 1024 blocks x 256 thr.
// ---------------------------------------------------------------------------
__global__ __launch_bounds__(256) void gated_rmsnorm(
    const float* __restrict__ y_ws, const unsigned short* __restrict__ proj,
    const float* __restrict__ nw, unsigned short* __restrict__ Y2) {
    __shared__ float red[4];
    int m = blockIdx.x, tid = threadIdx.x;
    const float* yrow = y_ws + (size_t)m * D_INNER;
    const unsigned short* zrow = proj + (size_t)m * PROJ_DIM;
    int j0 = tid * 8;
    ushort8 zv = *(const ushort8*)&zrow[j0];
    float v[8];
    float ss = 0.f;
    #pragma unroll
    for (int k = 0; k < 8; k++) {
        float y = yrow[j0 + k];
        float z = bf2f(zv[k]);
        float g = y * (z / (1.f + expf(-z)));
        v[k] = g;
        ss += g * g;
    }
    #pragma unroll
    for (int d = 32; d > 0; d >>= 1) ss += __shfl_down(ss, d, 64);
    if ((tid & 63) == 0) red[tid >> 6] = ss;
    __syncthreads();
    float tot = red[0] + red[1] + red[2] + red[3];
    float inv = 1.0f / sqrtf(tot / (float)D_INNER + 1e-6f);
    #pragma unroll
    for (int k = 0; k < 8; k++)
        Y2[(size_t)m * D_INNER + j0 + k] = f2bf(v[k] * inv * nw[j0 + k]);
}

// ---------------------------------------------------------------------------

extern "C" void kernel_launch(void* const* d_in, const int* in_sizes, int n_in,
                              void* d_out, int out_size, void* d_ws, size_t ws_size,
                              hipStream_t stream) {
    const float* hidden   = (const float*)d_in[0];
    const float* W_in     = (const float*)d_in[1];
    const float* dt_bias  = (const float*)d_in[2];
    const float* A_log    = (const float*)d_in[3];
    const float* norm_w   = (const float*)d_in[4];
    const float* W_out    = (const float*)d_in[5];
    float* out = (float*)d_out;

    char* ws = (char*)d_ws;
    unsigned short* Wt1  = (unsigned short*)(ws);                // 8320*1024 bf16 = 17,039,360
    unsigned short* Hb   = (unsigned short*)(ws + 17039360);     // 1024*1024 bf16 = 2,097,152
    unsigned short* proj = (unsigned short*)(ws + 19136512);     // 1024*8224 bf16 = 16,842,752
    float* dt_arr        = (float*)(ws + 35979264);              // 131,072
    float* cum_arr       = (float*)(ws + 36110336);              // 131,072
    unsigned short* Bh   = (unsigned short*)(ws + 36241408);     // 4,194,304
    unsigned short* Ch   = (unsigned short*)(ws + 40435712);     // 4,194,304
    unsigned short* Xt   = (unsigned short*)(ws + 44630016);     // 4,194,304
    float* y_ws          = (float*)(ws + 48824320);              // 1024*2048 f32 = 8,388,608
    unsigned short* Y2   = (unsigned short*)(ws + 57212928);     // 4,194,304
    unsigned short* Wt2  = (unsigned short*)(ws + 61407232);     // 4,194,304
    // total 65,601,536 bytes
    float* Pk = (float*)proj;  // 16 MB of split-K partials fits in 16.8 MB proj (free by then)

    // prep: hidden cast (1024) + Wt1 transpose (2080) + Wt2 transpose (512)
    prep_fat<<<3616, 256, 0, stream>>>(hidden, W_in, W_out, Hb, Wt1, Wt2);
    // proj = hidden @ W_in (bf16 out, guarded at N=8224)
    gemm_bt<true><<<dim3(NPAD / 128, MROWS / 128, 1), 256, 0, stream>>>(
        Hb, Wt1, proj, MROWS, PROJ_DIM, D_MODEL, D_MODEL);
    // dt scan + rope pack + x transpose, one block per (b,h)
    headprep<<<64, 256, 0, stream>>>(proj, dt_bias, dt_arr, cum_arr, Bh, Ch, Xt);
    // decay attention (the scan, reformulated)
    attn_scan<<<dim3(8, 64), 256, 0, stream>>>(Bh, Ch, Xt, dt_arr, cum_arr, A_log, y_ws);
    // gate + rmsnorm (last reader of proj/z)
    gated_rmsnorm<<<MROWS, 256, 0, stream>>>(y_ws, proj, norm_w, Y2);
    // out = Y2 @ W_out, split-K=4 partials into Pk, then reduce
    gemm_bt<false><<<dim3(D_MODEL / 128, MROWS / 128, 4), 256, 0, stream>>>(
        Y2, Wt2, Pk, MROWS, D_MODEL, D_INNER, D_INNER / 4);
    reduce4<<<MROWS * D_MODEL / 1024, 256, 0, stream>>>(Pk, out, MROWS * D_MODEL);
}

// Round 7
// 194.535 us; speedup vs baseline: 1.1284x; 1.0846x over previous
//
#include <hip/hip_runtime.h>
#include <stdint.h>

typedef __attribute__((ext_vector_type(8))) short short8;
typedef __attribute__((ext_vector_type(8))) unsigned short ushort8;
typedef __attribute__((ext_vector_type(4))) unsigned short usv4;
typedef __attribute__((ext_vector_type(4))) float float4v;

#define B_SZ 2
#define SEQ 512
#define D_MODEL 1024
#define D_INNER 2048
#define N_HEADS 32
#define HEAD_DIM 64
#define D_STATE 64
#define PROJ_DIM 8224   // 2*2048 + 2*2048 + 32
#define NPAD 8320       // 65*128
#define MROWS 1024      // B_SZ*SEQ

__device__ __forceinline__ unsigned short f2bf(float f) {
    unsigned u = __builtin_bit_cast(unsigned, f);
    u += 0x7fffu + ((u >> 16) & 1u);
    return (unsigned short)(u >> 16);
}
__device__ __forceinline__ float bf2f(unsigned short h) {
    return __builtin_bit_cast(float, (unsigned)h << 16);
}

// Async global->LDS 16B (m97 path). LDS dest must be wave-uniform base + lane*16.
__device__ __forceinline__ void gld16(unsigned short* lds, const unsigned short* g) {
#if __has_builtin(__builtin_amdgcn_global_load_lds)
    __builtin_amdgcn_global_load_lds(
        (const __attribute__((address_space(1))) void*)g,
        (__attribute__((address_space(3))) void*)lds, 16, 0, 0);
#else
    *(short8*)lds = *(const short8*)g;
#endif
}

// ---------------------------------------------------------------------------
// Fat prep kernel: blk<1024 -> hidden f32->bf16; then Wt1 transpose (2080
// blocks); then Wt2 transpose (512 blocks).
// ---------------------------------------------------------------------------
__device__ void transpose_body(const float* __restrict__ src,
                               unsigned short* __restrict__ dst,
                               int R, int C, int bx, int by, float* T, int tid) {
    int c0 = bx * 64, r0 = by * 64;
    int row = tid >> 2, cg = (tid & 3) * 16;
    #pragma unroll
    for (int k = 0; k < 4; k++) {
        int col = cg + k * 4;
        float4v v;
        if (c0 + col + 3 < C) {
            v = *(const float4v*)&src[(size_t)(r0 + row) * C + c0 + col];
        } else {
            #pragma unroll
            for (int e = 0; e < 4; e++)
                v[e] = (c0 + col + e < C) ? src[(size_t)(r0 + row) * C + c0 + col + e] : 0.f;
        }
        *(float4v*)&T[row * 68 + col] = v;
    }
    __syncthreads();
    int drow = tid >> 2, sg = (tid & 3) * 16;
    ushort8 v[2];
    #pragma unroll
    for (int k = 0; k < 16; k++) v[k >> 3][k & 7] = f2bf(T[(sg + k) * 68 + drow]);
    unsigned short* d = &dst[(size_t)(c0 + drow) * R + r0 + sg];
    *(ushort8*)&d[0] = v[0];
    *(ushort8*)&d[8] = v[1];
}

__global__ __launch_bounds__(256) void prep_fat(
    const float* __restrict__ hidden, const float* __restrict__ W_in,
    const float* __restrict__ W_out, unsigned short* __restrict__ Hb,
    unsigned short* __restrict__ Wt1, unsigned short* __restrict__ Wt2) {
    __shared__ float T[64 * 68];
    int blk = blockIdx.x, tid = threadIdx.x;
    if (blk < 1024) {
        int i = blk * 1024 + tid * 4;
        float4v v = *(const float4v*)&hidden[i];
        usv4 o;
        #pragma unroll
        for (int k = 0; k < 4; k++) o[k] = f2bf(v[k]);
        *(usv4*)&Hb[i] = o;
    } else if (blk < 3104) {
        int q = blk - 1024;  // 2080 = 130 x 16
        transpose_body(W_in, Wt1, D_MODEL, PROJ_DIM, q % 130, q / 130, T, tid);
    } else {
        int q = blk - 3104;  // 512 = 16 x 32
        transpose_body(W_out, Wt2, D_INNER, D_MODEL, q % 16, q / 16, T, tid);
    }
}

// ---------------------------------------------------------------------------
// GEMM: C[M][N] = A[M][K] @ Bt[N][K]^T (bf16). 128x128 tile, 4 waves, BK=64,
// async global_load_lds + XOR bank swizzle (conflict-free, verified R5).
// Split-K via gridDim.z; BF16OUT selects output type.
// ---------------------------------------------------------------------------
template <bool BF16OUT>
__global__ __launch_bounds__(256) void gemm_bt(
    const unsigned short* __restrict__ A, const unsigned short* __restrict__ Bt,
    void* __restrict__ Cout, int M, int N, int K, int klen) {
    __shared__ unsigned short As[8192];
    __shared__ unsigned short Bs[8192];
    int tid = threadIdx.x;
    int lane = tid & 63, w = tid >> 6, quad = lane >> 4, l15 = lane & 15;
    int m0 = blockIdx.y * 128, n0 = blockIdx.x * 128;
    int kb = blockIdx.z * klen, ke = kb + klen;
    int wm = (w & 1) * 64, wn = (w >> 1) * 64;
    float4v acc[4][4];
    #pragma unroll
    for (int i = 0; i < 4; i++)
        #pragma unroll
        for (int j = 0; j < 4; j++) acc[i][j] = (float4v){0.f, 0.f, 0.f, 0.f};

    int rs = tid >> 3;
    int gl = ((tid & 7) ^ (rs & 7)) * 8;
    const unsigned short* ap = &A [(size_t)(m0 + rs) * K + gl];
    const unsigned short* bp = &Bt[(size_t)(n0 + rs) * K + gl];
    int rx = l15 & 7;

    for (int k0 = kb; k0 < ke; k0 += 64) {
        __syncthreads();
        #pragma unroll
        for (int p = 0; p < 4; p++) {
            gld16(&As[p * 2048 + tid * 8], ap + (size_t)(p * 32) * K + k0);
            gld16(&Bs[p * 2048 + tid * 8], bp + (size_t)(p * 32) * K + k0);
        }
        __syncthreads();
        #pragma unroll
        for (int kq = 0; kq < 2; kq++) {
            short8 af[4], bfr[4];
            #pragma unroll
            for (int mt = 0; mt < 4; mt++)
                af[mt] = *(const short8*)&As[(wm + mt * 16 + l15) * 64 + (((kq << 2) + quad) ^ rx) * 8];
            #pragma unroll
            for (int nt = 0; nt < 4; nt++)
                bfr[nt] = *(const short8*)&Bs[(wn + nt * 16 + l15) * 64 + (((kq << 2) + quad) ^ rx) * 8];
            #pragma unroll
            for (int mt = 0; mt < 4; mt++)
                #pragma unroll
                for (int nt = 0; nt < 4; nt++)
                    acc[mt][nt] = __builtin_amdgcn_mfma_f32_16x16x32_bf16(
                        af[mt], bfr[nt], acc[mt][nt], 0, 0, 0);
        }
    }
    #pragma unroll
    for (int mt = 0; mt < 4; mt++)
        #pragma unroll
        for (int nt = 0; nt < 4; nt++)
            #pragma unroll
            for (int r = 0; r < 4; r++) {
                int row = m0 + wm + mt * 16 + quad * 4 + r;
                int col = n0 + wn + nt * 16 + l15;
                if (col < N) {
                    if (BF16OUT)
                        ((unsigned short*)Cout)[(size_t)blockIdx.z * M * N + (size_t)row * N + col]
                            = f2bf(acc[mt][nt][r]);
                    else
                        ((float*)Cout)[(size_t)blockIdx.z * M * N + (size_t)row * N + col]
                            = acc[mt][nt][r];
                }
            }
}

// ---------------------------------------------------------------------------
// reduce 4 split-K partials -> f32 out.
// ---------------------------------------------------------------------------
__global__ __launch_bounds__(256) void reduce4(
    const float* __restrict__ P, float* __restrict__ out, int n) {
    int i = (blockIdx.x * 256 + threadIdx.x) * 4;
    float4v s = *(const float4v*)&P[i];
    #pragma unroll
    for (int z = 1; z < 4; z++) {
        float4v v = *(const float4v*)&P[(size_t)z * n + i];
        #pragma unroll
        for (int k = 0; k < 4; k++) s[k] += v[k];
    }
    *(float4v*)&out[i] = s;
}

// ---------------------------------------------------------------------------
// dt softplus + cumsum per (b,h): 64 blocks x 256 threads (4 waves x 2
// chunks), 2-round parallel prefix (wave scans + 8-entry chunk-total scan).
// ---------------------------------------------------------------------------
__global__ __launch_bounds__(256) void dt_scan(
    const unsigned short* __restrict__ proj, const float* __restrict__ dt_bias,
    float* __restrict__ dt_arr, float* __restrict__ cum_arr) {
    __shared__ float chs[8];
    int bh = blockIdx.x;
    int b = bh >> 5, h = bh & 31;
    int tid = threadIdx.x, lane = tid & 63, w = tid >> 6;
    float bias = dt_bias[h];
    int t0 = w * 64 + lane, t1 = 256 + w * 64 + lane;
    float raw0 = bf2f(proj[(size_t)(b * SEQ + t0) * PROJ_DIM + 8192 + h]) + bias;
    float raw1 = bf2f(proj[(size_t)(b * SEQ + t1) * PROJ_DIM + 8192 + h]) + bias;
    float dt0 = raw0 > 20.f ? raw0 : log1pf(expf(raw0));
    float dt1 = raw1 > 20.f ? raw1 : log1pf(expf(raw1));
    float v0 = dt0, v1 = dt1;
    #pragma unroll
    for (int d = 1; d < 64; d <<= 1) {
        float n0 = __shfl_up(v0, d, 64);
        float n1 = __shfl_up(v1, d, 64);
        if (lane >= d) { v0 += n0; v1 += n1; }
    }
    if (lane == 63) { chs[w] = v0; chs[4 + w] = v1; }
    __syncthreads();
    float off0 = 0.f, off1 = 0.f;
    #pragma unroll
    for (int c = 0; c < 8; c++) {
        float s = chs[c];
        if (c < w) off0 += s;
        if (c < 4 + w) off1 += s;
    }
    dt_arr[bh * SEQ + t0] = dt0;  cum_arr[bh * SEQ + t0] = off0 + v0;
    dt_arr[bh * SEQ + t1] = dt1;  cum_arr[bh * SEQ + t1] = off1 + v1;
}

// ---------------------------------------------------------------------------
// pack_fat: blk<1024 -> RoPE pack B,C for row m=blk (b,t); else x-transpose
// chunk (512 blocks: bh = q>>3, s-chunk = q&7) -> Xt[bh][p][s] bf16.
// ---------------------------------------------------------------------------
__global__ __launch_bounds__(256) void pack_fat(
    const unsigned short* __restrict__ proj, const float* __restrict__ cum_arr,
    unsigned short* __restrict__ Bh, unsigned short* __restrict__ Ch,
    unsigned short* __restrict__ Xt) {
    __shared__ unsigned short XT[64 * 72];
    int blk = blockIdx.x, tid = threadIdx.x;
    if (blk < 1024) {
        int m = blk, b = m >> 9, t = m & 511;
        const float k_l2 = 13.287712379549449f / 32.f;  // log2(10000)/half
        #pragma unroll
        for (int i = 0; i < 4; i++) {
            int q = i * 256 + tid;
            int h = q >> 5, j = q & 31;
            float cum = cum_arr[(b * 32 + h) * SEQ + t];
            float th = cum * exp2f(-(float)j * k_l2);
            float s, c;
            __sincosf(th, &s, &c);
            size_t rb = (size_t)m * PROJ_DIM;
            unsigned bu = *(const unsigned*)&proj[rb + 4096 + h * 64 + 2 * j];
            unsigned cu = *(const unsigned*)&proj[rb + 6144 + h * 64 + 2 * j];
            float b0 = bf2f((unsigned short)(bu & 0xffff)), b1 = bf2f((unsigned short)(bu >> 16));
            float c0 = bf2f((unsigned short)(cu & 0xffff)), c1 = bf2f((unsigned short)(cu >> 16));
            size_t dst = ((size_t)(b * 32 + h) * SEQ + t) * 64 + 2 * j;
            unsigned ob = (unsigned)f2bf(b0 * c - b1 * s) | ((unsigned)f2bf(b0 * s + b1 * c) << 16);
            unsigned oc = (unsigned)f2bf(c0 * c - c1 * s) | ((unsigned)f2bf(c0 * s + c1 * c) << 16);
            *(unsigned*)&Bh[dst] = ob;
            *(unsigned*)&Ch[dst] = oc;
        }
    } else {
        int q = blk - 1024;
        int bh = q >> 3, s0 = (q & 7) * 64;
        int b = bh >> 5, h = bh & 31;
        int r = tid >> 2, cg = (tid & 3) * 16;
        const unsigned short* src = &proj[(size_t)(b * SEQ + s0 + r) * PROJ_DIM + 2048 + h * 64 + cg];
        *(ushort8*)&XT[r * 72 + cg]     = *(const ushort8*)&src[0];
        *(ushort8*)&XT[r * 72 + cg + 8] = *(const ushort8*)&src[8];
        __syncthreads();
        int p = tid >> 2, sg = (tid & 3) * 16;
        ushort8 v[2];
        #pragma unroll
        for (int k = 0; k < 16; k++) v[k >> 3][k & 7] = XT[(sg + k) * 72 + p];
        unsigned short* dst = &Xt[((size_t)bh * 64 + p) * SEQ + s0 + sg];
        *(ushort8*)&dst[0] = v[0];
        *(ushort8*)&dst[8] = v[1];
    }
}

// ---------------------------------------------------------------------------
// Decay-attention: y[b,t,h*64+p] = sum_{s<=t} exp(A(ct-cs))*0.5*(dt_s+[s<t]dt_{s+1})
//                                   * (C_t . B_s) * x_s[p]
// grid (8 q-tiles, 64 bh), 256 threads (4 waves x 16 q-rows).
// ---------------------------------------------------------------------------
__global__ __launch_bounds__(256) void attn_scan(
    const unsigned short* __restrict__ Bh, const unsigned short* __restrict__ Ch,
    const unsigned short* __restrict__ Xt, const float* __restrict__ dt_arr,
    const float* __restrict__ cum_arr, const float* __restrict__ A_log,
    float* __restrict__ y_ws) {
    __shared__ unsigned short Bs[4096];
    __shared__ unsigned short Xs[4096];
    __shared__ unsigned short Ps[4096];
    int qt = blockIdx.x, bh = blockIdx.y;
    int b = bh >> 5, h = bh & 31;
    float Aneg = -expf(A_log[h]);
    int tid = threadIdx.x, lane = tid & 63, w = tid >> 6;
    int quad = lane >> 4, l15 = lane & 15;

    int qrow = qt * 64 + w * 16 + l15;
    const unsigned short* Cptr = Ch + ((size_t)bh * SEQ + qrow) * 64;
    short8 cf[2];
    cf[0] = *(const short8*)&Cptr[quad * 8];
    cf[1] = *(const short8*)&Cptr[32 + quad * 8];

    int trow[4];
    float cumt[4];
    #pragma unroll
    for (int r = 0; r < 4; r++) {
        trow[r] = qt * 64 + w * 16 + quad * 4 + r;
        cumt[r] = cum_arr[bh * SEQ + trow[r]];
    }
    float4v yacc[4];
    #pragma unroll
    for (int i = 0; i < 4; i++) yacc[i] = (float4v){0.f, 0.f, 0.f, 0.f};

    for (int st = 0; st <= qt; st++) {
        __syncthreads();
        const unsigned short* bsrc = Bh + ((size_t)bh * SEQ + st * 64) * 64;
        gld16(&Bs[tid * 8],         bsrc + tid * 8);
        gld16(&Bs[(tid + 256) * 8], bsrc + (tid + 256) * 8);
        const unsigned short* xsrc = Xt + (size_t)bh * 64 * SEQ + st * 64;
        {
            int e = tid;
            int p = e >> 3, so = (e & 7) * 8;
            gld16(&Xs[p * 64 + so], xsrc + (size_t)p * SEQ + so);
            e = tid + 256;
            p = e >> 3; so = (e & 7) * 8;
            gld16(&Xs[p * 64 + so], xsrc + (size_t)p * SEQ + so);
        }
        __syncthreads();
        float4v sacc[4];
        #pragma unroll
        for (int i = 0; i < 4; i++) sacc[i] = (float4v){0.f, 0.f, 0.f, 0.f};
        #pragma unroll
        for (int kk = 0; kk < 2; kk++)
            #pragma unroll
            for (int nt = 0; nt < 4; nt++) {
                short8 bf8 = *(const short8*)&Bs[(nt * 16 + l15) * 64 + kk * 32 + quad * 8];
                sacc[nt] = __builtin_amdgcn_mfma_f32_16x16x32_bf16(cf[kk], bf8, sacc[nt], 0, 0, 0);
            }
        #pragma unroll
        for (int nt = 0; nt < 4; nt++) {
            int s = st * 64 + nt * 16 + l15;
            float cums = cum_arr[bh * SEQ + s];
            float dts = dt_arr[bh * SEQ + s];
            float dts1 = (s + 1 < SEQ) ? dt_arr[bh * SEQ + s + 1] : 0.f;
            #pragma unroll
            for (int r = 0; r < 4; r++) {
                int t = trow[r];
                float wgt = (s > t) ? 0.f
                          : expf(Aneg * (cumt[r] - cums)) * 0.5f * (dts + ((s < t) ? dts1 : 0.f));
                Ps[w * 1024 + (quad * 4 + r) * 64 + nt * 16 + l15] = f2bf(sacc[nt][r] * wgt);
            }
        }
        __syncthreads();
        #pragma unroll
        for (int kk = 0; kk < 2; kk++) {
            short8 af = *(const short8*)&Ps[w * 1024 + l15 * 64 + kk * 32 + quad * 8];
            #pragma unroll
            for (int pt = 0; pt < 4; pt++) {
                short8 xf = *(const short8*)&Xs[(pt * 16 + l15) * 64 + kk * 32 + quad * 8];
                yacc[pt] = __builtin_amdgcn_mfma_f32_16x16x32_bf16(af, xf, yacc[pt], 0, 0, 0);
            }
        }
    }
    #pragma unroll
    for (int pt = 0; pt < 4; pt++)
        #pragma unroll
        for (int r = 0; r < 4; r++) {
            int t = trow[r];
            int p = pt * 16 + l15;
            y_ws[((size_t)b * SEQ + t) * D_INNER + h * 64 + p] = yacc[pt][r];
        }
}

// ---------------------------------------------------------------------------
// y = y*silu(z); rmsnorm; write bf16. z from bf16 proj. 1024 blocks x 256 thr.
// ---------------------------------------------------------------------------
__global__ __launch_bounds__(256) void gated_rmsnorm(
    const float* __restrict__ y_ws, const unsigned short* __restrict__ proj,
    const float* __restrict__ nw, unsigned short* __restrict__ Y2) {
    __shared__ float red[4];
    int m = blockIdx.x, tid = threadIdx.x;
    const float* yrow = y_ws + (size_t)m * D_INNER;
    const unsigned short* zrow = proj + (size_t)m * PROJ_DIM;
    int j0 = tid * 8;
    ushort8 zv = *(const ushort8*)&zrow[j0];
    float v[8];
    float ss = 0.f;
    #pragma unroll
    for (int k = 0; k < 8; k++) {
        float y = yrow[j0 + k];
        float z = bf2f(zv[k]);
        float g = y * (z / (1.f + expf(-z)));
        v[k] = g;
        ss += g * g;
    }
    #pragma unroll
    for (int d = 32; d > 0; d >>= 1) ss += __shfl_down(ss, d, 64);
    if ((tid & 63) == 0) red[tid >> 6] = ss;
    __syncthreads();
    float tot = red[0] + red[1] + red[2] + red[3];
    float inv = 1.0f / sqrtf(tot / (float)D_INNER + 1e-6f);
    #pragma unroll
    for (int k = 0; k < 8; k++)
        Y2[(size_t)m * D_INNER + j0 + k] = f2bf(v[k] * inv * nw[j0 + k]);
}

// ---------------------------------------------------------------------------

extern "C" void kernel_launch(void* const* d_in, const int* in_sizes, int n_in,
                              void* d_out, int out_size, void* d_ws, size_t ws_size,
                              hipStream_t stream) {
    const float* hidden   = (const float*)d_in[0];
    const float* W_in     = (const float*)d_in[1];
    const float* dt_bias  = (const float*)d_in[2];
    const float* A_log    = (const float*)d_in[3];
    const float* norm_w   = (const float*)d_in[4];
    const float* W_out    = (const float*)d_in[5];
    float* out = (float*)d_out;

    char* ws = (char*)d_ws;
    unsigned short* Wt1  = (unsigned short*)(ws);                // 8320*1024 bf16 = 17,039,360
    unsigned short* Hb   = (unsigned short*)(ws + 17039360);     // 1024*1024 bf16 = 2,097,152
    unsigned short* proj = (unsigned short*)(ws + 19136512);     // 1024*8224 bf16 = 16,842,752
    float* dt_arr        = (float*)(ws + 35979264);              // 131,072
    float* cum_arr       = (float*)(ws + 36110336);              // 131,072
    unsigned short* Bh   = (unsigned short*)(ws + 36241408);     // 4,194,304
    unsigned short* Ch   = (unsigned short*)(ws + 40435712);     // 4,194,304
    unsigned short* Xt   = (unsigned short*)(ws + 44630016);     // 4,194,304
    float* y_ws          = (float*)(ws + 48824320);              // 1024*2048 f32 = 8,388,608
    unsigned short* Y2   = (unsigned short*)(ws + 57212928);     // 4,194,304
    unsigned short* Wt2  = (unsigned short*)(ws + 61407232);     // 4,194,304
    // total 65,601,536 bytes
    float* Pk = (float*)proj;  // 16 MB split-K partials fit in 16.8 MB proj (free by then)

    // prep: hidden cast (1024) + Wt1 transpose (2080) + Wt2 transpose (512)
    prep_fat<<<3616, 256, 0, stream>>>(hidden, W_in, W_out, Hb, Wt1, Wt2);
    // proj = hidden @ W_in (bf16 out, guarded at N=8224)
    gemm_bt<true><<<dim3(NPAD / 128, MROWS / 128, 1), 256, 0, stream>>>(
        Hb, Wt1, proj, MROWS, PROJ_DIM, D_MODEL, D_MODEL);
    // dt + cumsum (2-round parallel prefix)
    dt_scan<<<64, 256, 0, stream>>>(proj, dt_bias, dt_arr, cum_arr);
    // rope pack (1024) + x transpose (512)
    pack_fat<<<1536, 256, 0, stream>>>(proj, cum_arr, Bh, Ch, Xt);
    // decay attention (the scan, reformulated)
    attn_scan<<<dim3(8, 64), 256, 0, stream>>>(Bh, Ch, Xt, dt_arr, cum_arr, A_log, y_ws);
    // gate + rmsnorm (last reader of proj/z)
    gated_rmsnorm<<<MROWS, 256, 0, stream>>>(y_ws, proj, norm_w, Y2);
    // out = Y2 @ W_out, split-K=4 partials into Pk, then reduce
    gemm_bt<false><<<dim3(D_MODEL / 128, MROWS / 128, 4), 256, 0, stream>>>(
        Y2, Wt2, Pk, MROWS, D_MODEL, D_INNER, D_INNER / 4);
    reduce4<<<MROWS * D_MODEL / 1024, 256, 0, stream>>>(Pk, out, MROWS * D_MODEL);
}